// Round 15
// baseline (2323.058 us; speedup 1.0000x reference)
//
#include <hip/hip_runtime.h>
#include <hip/hip_bf16.h>

#define V_SZ 100000
#define E_SZ 128
#define H_SZ 512
#define L_SZ 9
#define B_SZ 64
#define T_SZ 512
#define G4   (4*H_SZ)

#define LOGITS_N (B_SZ*T_SZ*L_SZ)            // 294912
#define HS_BYTES ((size_t)B_SZ*T_SZ*H_SZ*2)  // 33554432 (hs2 same total size)
#define PAGE_B 8192                          // bytes per (g,t) page: 16kk x 4q x 8row x 16B
#define SENT32 0x7FC07FC0u
#define SENT64 0x7FC07FC07FC07FC0ull

typedef short bf16x8 __attribute__((ext_vector_type(8)));
typedef float f32x4  __attribute__((ext_vector_type(4)));
typedef unsigned long long u64x2 __attribute__((ext_vector_type(2)));

static __device__ __forceinline__ unsigned short f2bf(float x){
  unsigned int u = __builtin_bit_cast(unsigned int, x);
  unsigned int r = (u + 0x7fffu + ((u >> 16) & 1u)) >> 16;
  return (unsigned short)r;
}
static __device__ __forceinline__ float bf2f(unsigned short b){
  unsigned int u = ((unsigned int)b) << 16;
  return __builtin_bit_cast(float, u);
}
static __device__ __forceinline__ float sig_f(float x){
  return 1.f / (1.f + __expf(-x));
}
static __device__ __forceinline__ float tanh_f(float x){
  float a = fabsf(x);
  float e = __expf(-2.f * a);
  float t = (1.f - e) / (1.f + e);
  return copysignf(t, x);
}

// ---------------- reset hs2 to sentinel (graph replays don't re-poison) -----
__global__ void k_reset(unsigned long long* __restrict__ hs64){
  const long n = HS_BYTES / 8;
  for (long i = (long)blockIdx.x*256 + threadIdx.x; i < n; i += (long)gridDim.x*256)
    __hip_atomic_store(&hs64[i], SENT64, __ATOMIC_RELAXED, __HIP_MEMORY_SCOPE_AGENT);
}

// ---------------- lens ----------------
__global__ void k_lens(const int* __restrict__ text, float* __restrict__ out_lens){
  int b = blockIdx.x;
  int c = 0;
  for (int t = threadIdx.x; t < T_SZ; t += 256)
    c += (text[b*T_SZ + t] != 0);
  for (int off = 32; off; off >>= 1) c += __shfl_down(c, off, 64);
  __shared__ int sred[4];
  int w = threadIdx.x >> 6;
  if ((threadIdx.x & 63) == 0) sred[w] = c;
  __syncthreads();
  if (threadIdx.x == 0)
    out_lens[b] = (float)(sred[0] + sred[1] + sred[2] + sred[3]);
}

// ---------------- fused embed + xg + LSTM recurrence (wave-agents, v2) ------
// r10's barrier-free/LDS-free wave-agent frame (correctness-proven) with its
// single defect — uncoalesced polls — fixed by a TRANSPOSED exchange layout:
//   hs2[g][t][kk][q][row<8][8 bf16]   (page = 8 KB per (g,t))
// A consuming wave's poll of chunk kk is a contiguous 512B load across its
// active lanes (lane (q,l16<8) reads kk*512 + q*128 + l16*16, two u64 atomic
// loads) STRAIGHT into MFMA A-frag registers. No LDS, no barriers in the
// loop; each wave exits its poll independently; post-arrival tail = 16
// h-MFMAs + gates. Producer: the existing 4-col 8B pack per row stores to
// one transposed address (8 stores/wave, contiguous 256B per block-page).
// Grid/geometry identical to r7: 8 groups x 32 blocks x 4 waves; wave w of
// block j owns cols c0 = 16j + 4w .. +4. Coherence ops identical to r2-r14:
// relaxed agent 8B atomics, data-is-flag (bf16-NaN sentinel).
__global__ __launch_bounds__(256, 1)
void k_lstm(const int* __restrict__ text, const float* __restrict__ embed,
            const float* __restrict__ Wx, const float* __restrict__ Wh,
            const float* __restrict__ bias, unsigned short* __restrict__ hs2)
{
  const int g    = blockIdx.x & 7;     // group (intended XCD), seqs [8g, 8g+8)
  const int j    = blockIdx.x >> 3;    // 0..31 block-in-group
  const int n0   = j * 16;
  const int tid  = threadIdx.x;
  const int w    = tid >> 6;           // wave id 0..3
  const int lane = tid & 63;
  const int q    = lane >> 4;
  const int l16  = lane & 15;
  const int gate = l16 & 3;            // B-col -> gate
  const int cq   = l16 >> 2;           // B-col -> col-in-wave 0..3

  // ---- weight B-frags (permuted): W[(kk*32 + q*8 + jj)][gate*H + hcol] ----
  const int hcol = n0 + w*4 + cq;
  const int gcol = gate*H_SZ + hcol;
  bf16x8 Whf[16];
#pragma unroll
  for (int kk = 0; kk < 16; ++kk){
    bf16x8 v;
#pragma unroll
    for (int jj = 0; jj < 8; ++jj)
      v[jj] = (short)f2bf(Wh[(long)(kk*32 + q*8 + jj)*G4 + gcol]);
    Whf[kk] = v;
  }
  bf16x8 Wxf[4];
#pragma unroll
  for (int kk = 0; kk < 4; ++kk){
    bf16x8 v;
#pragma unroll
    for (int jj = 0; jj < 8; ++jj)
      v[jj] = (short)f2bf(Wx[(long)(kk*32 + q*8 + jj)*G4 + gcol]);
    Wxf[kk] = v;
  }
  const float biasv = bias[gcol];

  float cs[4] = {0.f, 0.f, 0.f, 0.f};   // rows q*4+rg of col cq (gate-redundant)
  const bool isPub = (gate == 0) && (cq == 0) && (q < 2);

  // publish: wave w covers cols c0..c0+3; one 8B unit at transposed address
  const int c0  = n0 + w*4;
  const int kkp = c0 >> 5;
  const int qp  = (c0 >> 3) & 3;
  const int jj0 = c0 & 7;               // 0 or 4
  char* pub = (char*)hs2 + ((long)g*T_SZ)*PAGE_B + kkp*512 + qp*128 + jj0*2;
  // per-row store addr: pub + (q*4+rg)*16 ; advance += PAGE_B per t

  // poll base (valid l16 < 8): lane (q,l16) reads chunk kk at kk*512+q*128+l16*16
  const char* pollb = (const char*)hs2 + ((long)g*T_SZ)*PAGE_B + q*128 + l16*16;

  // token row pointer (valid for l16 < 8)
  const int* tokp = text + (g*8 + (l16 & 7))*T_SZ;

  // ---- prologue: load + convert x for t=0 ----
  float4 xa[4], xb[4];
  bf16x8 xf[4];
#pragma unroll
  for (int kk = 0; kk < 4; ++kk) xf[kk] = (bf16x8){0,0,0,0,0,0,0,0};
  if (l16 < 8){
    int tok = tokp[0];
    const float* er = embed + (long)tok*E_SZ + q*8;
#pragma unroll
    for (int kk = 0; kk < 4; ++kk){
      xa[kk] = *(const float4*)(er + kk*32);
      xb[kk] = *(const float4*)(er + kk*32 + 4);
    }
#pragma unroll
    for (int kk = 0; kk < 4; ++kk){
      bf16x8 v;
      v[0] = (short)f2bf(xa[kk].x); v[1] = (short)f2bf(xa[kk].y);
      v[2] = (short)f2bf(xa[kk].z); v[3] = (short)f2bf(xa[kk].w);
      v[4] = (short)f2bf(xb[kk].x); v[5] = (short)f2bf(xb[kk].y);
      v[6] = (short)f2bf(xb[kk].z); v[7] = (short)f2bf(xb[kk].w);
      xf[kk] = v;
    }
  }

  unsigned long long h0[16], h1[16];
#pragma unroll
  for (int kk = 0; kk < 16; ++kk){ h0[kk] = 0ull; h1[kk] = 0ull; }

  for (int t = 0; t < T_SZ; ++t){
    // ---- issue x prefetch for t+1 (completes under the poll) ----
    const bool havex = (t + 1 < T_SZ) && (l16 < 8);
    if (havex){
      int tok = tokp[t + 1];
      const float* er = embed + (long)tok*E_SZ + q*8;
#pragma unroll
      for (int kk = 0; kk < 4; ++kk){
        xa[kk] = *(const float4*)(er + kk*32);
        xb[kk] = *(const float4*)(er + kk*32 + 4);
      }
    }

    // ---- poll h_{t-1} straight into A-frag regs (coalesced, data-is-flag) ----
    if (t > 0){
      const char* pb = pollb + (long)(t-1)*PAGE_B;
      int it = 0; bool ok;
      do {
        ok = true;
        if (l16 < 8){
#pragma unroll
          for (int kk = 0; kk < 16; ++kk){
            h0[kk] = __hip_atomic_load((const unsigned long long*)(pb + kk*512),
                                       __ATOMIC_RELAXED, __HIP_MEMORY_SCOPE_AGENT);
            h1[kk] = __hip_atomic_load((const unsigned long long*)(pb + kk*512 + 8),
                                       __ATOMIC_RELAXED, __HIP_MEMORY_SCOPE_AGENT);
          }
#pragma unroll
          for (int kk = 0; kk < 16; ++kk)
            ok = ok && ((unsigned int)h0[kk] != SENT32)
                    && ((unsigned int)h1[kk] != SENT32);
        }
      } while (!__all(ok) && ++it < (1 << 22));
    }

    // ---- MFMA: gates = x_t @ Wx (+ h_{t-1} @ Wh) + b ----
    f32x4 acc0 = {biasv, biasv, biasv, biasv};
    f32x4 acc1 = {0.f, 0.f, 0.f, 0.f};
#pragma unroll
    for (int kk = 0; kk < 4; ++kk){
      if (kk & 1) acc1 = __builtin_amdgcn_mfma_f32_16x16x32_bf16(xf[kk], Wxf[kk], acc1, 0, 0, 0);
      else        acc0 = __builtin_amdgcn_mfma_f32_16x16x32_bf16(xf[kk], Wxf[kk], acc0, 0, 0, 0);
    }
    if (t > 0){
#pragma unroll
      for (int kk = 0; kk < 16; ++kk){
        bf16x8 a = __builtin_bit_cast(bf16x8, (u64x2){h0[kk], h1[kk]});
        if (kk & 1) acc1 = __builtin_amdgcn_mfma_f32_16x16x32_bf16(a, Whf[kk], acc1, 0, 0, 0);
        else        acc0 = __builtin_amdgcn_mfma_f32_16x16x32_bf16(a, Whf[kk], acc0, 0, 0, 0);
      }
    }

    // ---- gates via quad shuffles; c,h; publish 8B transposed (data-is-flag) ----
    // C/D: col = l16 -> (gate, cq); row = q*4+rg (rows 0..7 real).
#pragma unroll
    for (int rg = 0; rg < 4; ++rg){
      float v  = acc0[rg] + acc1[rg];
      float x1 = __shfl_xor(v, 1, 64);
      float x2 = __shfl_xor(v, 2, 64);
      float x3 = __shfl_xor(v, 3, 64);
      float gi = (gate==0)? v : (gate==1)? x1 : (gate==2)? x2 : x3;
      float gf = (gate==1)? v : (gate==0)? x1 : (gate==3)? x2 : x3;
      float gc = (gate==2)? v : (gate==3)? x1 : (gate==0)? x2 : x3;
      float go = (gate==3)? v : (gate==2)? x1 : (gate==1)? x2 : x3;
      cs[rg] = sig_f(gf)*cs[rg] + sig_f(gi)*tanh_f(gc);
      float hv = sig_f(go)*tanh_f(cs[rg]);
      unsigned int hb  = (unsigned int)f2bf(hv);
      unsigned int pr  = (unsigned int)__shfl_xor((int)hb, 4, 64);  // col cq^1
      unsigned int pk  = hb | (pr << 16);                           // 2 cols
      unsigned int pk2 = (unsigned int)__shfl_xor((int)pk, 8, 64);  // cols cq^2
      unsigned long long p8 = (unsigned long long)pk
                            | ((unsigned long long)pk2 << 32);      // 4 cols
      if (isPub)
        __hip_atomic_store((unsigned long long*)(pub + (q*4 + rg)*16), p8,
                           __ATOMIC_RELAXED, __HIP_MEMORY_SCOPE_AGENT);
    }
    pub += PAGE_B;

    // ---- convert prefetched x_{t+1} into A-frags (loads done by now) ----
    if (havex){
#pragma unroll
      for (int kk = 0; kk < 4; ++kk){
        bf16x8 v;
        v[0] = (short)f2bf(xa[kk].x); v[1] = (short)f2bf(xa[kk].y);
        v[2] = (short)f2bf(xa[kk].z); v[3] = (short)f2bf(xa[kk].w);
        v[4] = (short)f2bf(xb[kk].x); v[5] = (short)f2bf(xb[kk].y);
        v[6] = (short)f2bf(xb[kk].z); v[7] = (short)f2bf(xb[kk].w);
        xf[kk] = v;
      }
    }
  }
}

// ---------------- logits = hs2 @ Wd + bd (reads transposed layout) ----------
// h[b][tt][k..k+7] = 16B unit at page(b>>3, tt) + (k/8)*128 + (b&7)*16.
__global__ void k_logits(const unsigned short* __restrict__ hs2,
                         const float* __restrict__ Wd, const float* __restrict__ bd,
                         float* __restrict__ out)
{
  __shared__ float wd_s[H_SZ*L_SZ];
  __shared__ float bd_s[L_SZ];
  for (int i = threadIdx.x; i < H_SZ*L_SZ; i += 128) wd_s[i] = Wd[i];
  if (threadIdx.x < L_SZ) bd_s[threadIdx.x] = bd[threadIdx.x];
  __syncthreads();

  long row = (long)blockIdx.x*128 + threadIdx.x;   // 0..32767 = b*T + tt
  int b  = (int)(row >> 9);
  int tt = (int)(row & 511);
  const char* base = (const char*)hs2
      + ((long)(b >> 3)*T_SZ + tt)*PAGE_B + (b & 7)*16;
  float acc[9];
#pragma unroll
  for (int jj = 0; jj < 9; ++jj) acc[jj] = 0.f;
  for (int k = 0; k < H_SZ; k += 8){
    uint4 v = *(const uint4*)(base + (long)k*16);
    const unsigned short* u = (const unsigned short*)&v;
#pragma unroll
    for (int l = 0; l < 8; ++l){
      float hf = bf2f(u[l]);
#pragma unroll
      for (int jj = 0; jj < 9; ++jj)
        acc[jj] = fmaf(hf, wd_s[(k + l)*L_SZ + jj], acc[jj]);
    }
  }
  float* op = out + row*L_SZ;
#pragma unroll
  for (int jj = 0; jj < 9; ++jj) op[jj] = acc[jj] + bd_s[jj];
}

// ---------------- CRF: score + forward algorithm ----------------
__global__ void k_crf(const float* __restrict__ logits, const int* __restrict__ labels,
                      const float* __restrict__ trans, const float* __restrict__ lensf,
                      float* __restrict__ out_ll)
{
  int b = blockIdx.x;
  int lane = threadIdx.x;             // 64 threads = 1 wave
  int len = (int)lensf[b];
  const float* lg  = logits + (long)b*T_SZ*L_SZ;
  const int*   lab = labels + b*T_SZ;

  float s = 0.f;
  for (int t = lane; t < T_SZ; t += 64){
    if (t < len){
      s += lg[t*L_SZ + lab[t]];
      if (t >= 1) s += trans[lab[t-1]*L_SZ + lab[t]];
    }
  }
  for (int off = 32; off; off >>= 1) s += __shfl_down(s, off, 64);

  float tr[9];
#pragma unroll
  for (int i = 0; i < 9; ++i) tr[i] = (lane < 9) ? trans[i*L_SZ + lane] : 0.f;
  float alpha = (lane < 9) ? lg[lane] : -1e30f;

  for (int t = 1; t < T_SZ; ++t){
    float tmp[9];
#pragma unroll
    for (int i = 0; i < 9; ++i){
      float ai = __shfl(alpha, i, 64);
      tmp[i] = ai + tr[i];
    }
    float m0 = fmaxf(fmaxf(tmp[0], tmp[1]), tmp[2]);
    float m1 = fmaxf(fmaxf(tmp[3], tmp[4]), tmp[5]);
    float m2 = fmaxf(fmaxf(tmp[6], tmp[7]), tmp[8]);
    float m  = fmaxf(fmaxf(m0, m1), m2);
    float e = 0.f;
#pragma unroll
    for (int i = 0; i < 9; ++i) e += __expf(tmp[i] - m);
    float lgv = (lane < 9) ? lg[t*L_SZ + lane] : 0.f;
    float nv = m + __logf(e) + lgv;
    if (t < len && lane < 9) alpha = nv;
  }

  float mm = (lane < 9) ? alpha : -1e30f;
  for (int off = 8; off; off >>= 1) mm = fmaxf(mm, __shfl_down(mm, off, 64));
  mm = __shfl(mm, 0, 64);
  float ee = (lane < 9) ? __expf(alpha - mm) : 0.f;
  for (int off = 8; off; off >>= 1) ee += __shfl_down(ee, off, 64);
  if (lane == 0) out_ll[b] = s - (mm + __logf(ee));
}

extern "C" void kernel_launch(void* const* d_in, const int* in_sizes, int n_in,
                              void* d_out, int out_size, void* d_ws, size_t ws_size,
                              hipStream_t stream)
{
  const int*   text   = (const int*)  d_in[0];
  const int*   labels = (const int*)  d_in[1];
  const float* embed  = (const float*)d_in[2];
  const float* Wx     = (const float*)d_in[3];
  const float* Wh     = (const float*)d_in[4];
  const float* bias   = (const float*)d_in[5];
  const float* Wd     = (const float*)d_in[6];
  const float* bd     = (const float*)d_in[7];
  const float* trans  = (const float*)d_in[8];

  float* out        = (float*)d_out;
  float* out_logits = out;
  float* out_lens   = out + LOGITS_N;
  float* out_ll     = out + LOGITS_N + B_SZ;

  unsigned short* hs2 = (unsigned short*)d_ws;

  k_reset <<<2048, 256, 0, stream>>>((unsigned long long*)hs2);
  k_lens  <<<B_SZ, 256, 0, stream>>>(text, out_lens);
  k_lstm  <<<256, 256, 0, stream>>>(text, embed, Wx, Wh, bias, hs2);
  k_logits<<<256, 128, 0, stream>>>(hs2, Wd, bd, out_logits);
  k_crf   <<<B_SZ, 64, 0, stream>>>(out_logits, labels, trans, out_lens, out_ll);
}